// Round 11
// baseline (158.455 us; speedup 1.0000x reference)
//
#include <hip/hip_runtime.h>
#include <math.h>

// Problem constants (from reference)
#define NB      2048        // batch
#define DIM     256         // input dim
#define SC6     192         // S*6 = 32 splines * 6 params
#define CV      128         // canvas size
#define NT      50          // samples along curve
#define NBPB    4           // batches per block (W amortization)
#define CWORDS  (CV * CV / 4)   // 4096 u8-packed words per canvas
// W_STAMP = -0.07, BG = 0.3, SCALE = 1e-4

// log_prob per batch = 192*( -ln(1e-4) - 0.5*ln(2*pi) )  (raw == mu exactly)
// entropy  per batch = 192*( 0.5 + 0.5*ln(2*pi) + ln(1e-4) )
#define LPV  (1591.9491530441301f)
#define ENV  (-1495.9491530441301f)

// Output layout (flat, return order): sketch | log_prob | entropy | sample
#define SKETCH_N   ((size_t)NB * CV * CV)     // 33,554,432
#define LP_OFF     (SKETCH_N)
#define ENT_OFF    (LP_OFF + NB)
#define SAMPLE_OFF (ENT_OFF + NB)

typedef float vfloat4 __attribute__((ext_vector_type(4)));

// Workgroup barrier waiting ONLY on LDS ops (lgkmcnt), not global stores —
// __syncthreads() would emit s_waitcnt vmcnt(0) and drain epilogue stores on
// the critical path. All cross-phase deps here are LDS-only.
__device__ __forceinline__ void barrier_lds_only() {
    asm volatile("s_waitcnt lgkmcnt(0)\n\ts_barrier" ::: "memory");
}

// Paint one batch's 32 splines into canvas cnv (u8-packed, per-row rotation).
__device__ __forceinline__ void do_paint(
    unsigned int* __restrict__ cnv,
    const double (* __restrict__ spb)[32],
    const double* __restrict__ cfa, const double* __restrict__ cfb,
    const double* __restrict__ cfc, int tid)
{
    for (int i = tid; i < 32 * NT; i += 512) {
        int s    = i & 31;
        int kraw = i >> 5;                    // 0..49
        int k    = (kraw * 9) % 50;           // bijection, spreads t per wave
        double a  = cfa[k];
        double bq = cfb[k];
        double c  = cfc[k];
        double px = a * spb[0][s] + bq * spb[2][s] + c * spb[4][s];
        double py = a * spb[1][s] + bq * spb[3][s] + c * spb[5][s];
        int cx = (int)rint(px);               // round-half-even == np.round
        int cy = (int)rint(py);

        // clipped y-triple -> u8 increments for 1-2 adjacent 4-px words
        int y0 = min(max(cy - 1, 0), CV - 1);
        int y1 = min(max(cy,     0), CV - 1);
        int y2 = min(max(cy + 1, 0), CV - 1);
        int cb = y0 >> 2;                     // base word-column (0..31)
        unsigned incA = 1u << ((y0 & 3) << 3);
        unsigned incB = 0u;
        unsigned i1 = 1u << ((y1 & 3) << 3);
        unsigned i2 = 1u << ((y2 & 3) << 3);
        if ((y1 >> 2) == cb) incA += i1; else incB += i1;
        if ((y2 >> 2) == cb) incA += i2; else incB += i2;

        int x0 = min(max(cx - 1, 0), CV - 1);
        int x1 = min(max(cx,     0), CV - 1);
        int x2 = min(max(cx + 1, 0), CV - 1);
        int rows[3] = {x0, x1, x2};
        #pragma unroll
        for (int r = 0; r < 3; ++r) {
            int xi = rows[r];
            int base = xi << 5;
            atomicAdd(&cnv[base + ((cb + xi) & 31)], incA);
            if (incB) atomicAdd(&cnv[base + ((cb + 1 + xi) & 31)], incB);
        }
    }
}

// Emit one batch's canvas: clip(0.3-0.07*count,0,1), float4 cached stores;
// re-zeros the canvas in passing (next paint into it needs zeros).
__device__ __forceinline__ void do_epilogue(
    unsigned int* __restrict__ cnv, float* __restrict__ outb, int tid)
{
    vfloat4* ob = (vfloat4*)outb;
    for (int w = tid; w < CWORDS; w += 512) {
        int xi  = w >> 5;                     // row
        int idx = (xi << 5) + (((w & 31) + xi) & 31);
        unsigned v = cnv[idx];
        cnv[idx] = 0u;
        vfloat4 r;
        r.x = fminf(fmaxf(0.3f - 0.07f * (float)( v        & 255u), 0.0f), 1.0f);
        r.y = fminf(fmaxf(0.3f - 0.07f * (float)((v >>  8) & 255u), 0.0f), 1.0f);
        r.z = fminf(fmaxf(0.3f - 0.07f * (float)((v >> 16) & 255u), 0.0f), 1.0f);
        r.w = fminf(fmaxf(0.3f - 0.07f * (float)( v >> 24        ), 0.0f), 1.0f);
        ob[w] = r;                            // cached store -> L2
    }
}

// ---------------------------------------------------------------------------
// Fused kernel, one block (512 thr) per FOUR batches; grid 512 = 2 blocks/CU.
// DOUBLE-BUFFERED canvases A/B pipeline the phases:
//   phase 0: gemm (waves 0-2, f64 bit-exact chains) || zero A+B, coeff table
//   phase k (k=1..3): epilogue(batch k-1) then IMMEDIATELY (no barrier)
//            paint(batch k) into the other canvas; one lgkm-only barrier.
//            -> store drain / VALU unpack of epi co-schedules with paint's
//            DS atomics across drifting waves; HBM never idles during paint.
//   tail:    epilogue(batch 3).
// Barriers: 5 (was 8), none waits on vmcnt.
// ---------------------------------------------------------------------------
__global__ __launch_bounds__(512) void fused_kernel(
    const float* __restrict__ x, const float* __restrict__ W,
    const float* __restrict__ bias, float* __restrict__ out)
{
    __shared__ unsigned int cnt[2][CWORDS];       // 2 × 16 KB u8-packed
    __shared__ double sp[NBPB][6][32];            // SoA params*128, 4 batches
    __shared__ double cfa[NT], cfb[NT], cfc[NT];  // (1-t)^2, 2(1-t)t, t^2

    const int b0  = blockIdx.x * NBPB;
    const int tid = threadIdx.x;

    if (tid < SC6) {
        // ---- gemm + sigmoid, 4 batches, W loaded once (f64 exact chains) ----
        const int j = tid;
        const float* xb = x + (size_t)b0 * DIM;   // wave-uniform -> s_load
        double a0 = 0.0, a1 = 0.0, a2 = 0.0, a3 = 0.0;
        #pragma unroll 8
        for (int d = 0; d < DIM; ++d) {
            double wd = (double)W[d * SC6 + j];
            a0 = fma((double)xb[d],           wd, a0);
            a1 = fma((double)xb[DIM + d],     wd, a1);
            a2 = fma((double)xb[2 * DIM + d], wd, a2);
            a3 = fma((double)xb[3 * DIM + d], wd, a3);
        }
        double bj = (double)bias[j];
        double s0 = 1.0 / (1.0 + exp(-(a0 + bj)));
        double s1 = 1.0 / (1.0 + exp(-(a1 + bj)));
        double s2 = 1.0 / (1.0 + exp(-(a2 + bj)));
        double s3 = 1.0 / (1.0 + exp(-(a3 + bj)));
        out[SAMPLE_OFF + (size_t)b0 * SC6 + j]       = (float)s0;
        out[SAMPLE_OFF + (size_t)(b0 + 1) * SC6 + j] = (float)s1;
        out[SAMPLE_OFF + (size_t)(b0 + 2) * SC6 + j] = (float)s2;
        out[SAMPLE_OFF + (size_t)(b0 + 3) * SC6 + j] = (float)s3;
        sp[0][j % 6][j / 6] = s0 * 128.0;         // CANVAS scale, SoA
        sp[1][j % 6][j / 6] = s1 * 128.0;
        sp[2][j % 6][j / 6] = s2 * 128.0;
        sp[3][j % 6][j / 6] = s3 * 128.0;
    } else {
        // ---- waves 3-7: zero BOTH canvases + coeff table + constants ----
        const int t2 = tid - SC6;                 // 0..319
        uint4* c4 = (uint4*)&cnt[0][0];           // 2048 uint4 words
        uint4 z = make_uint4(0u, 0u, 0u, 0u);
        for (int w = t2; w < 2048; w += 320) c4[w] = z;
        if (t2 < NT) {
            // np.linspace(0,1,50): t_k = k*fl64(1/49), endpoint forced to 1.0
            double t = (t2 == NT - 1) ? 1.0 : (double)t2 * (1.0 / 49.0);
            double u = 1.0 - t;
            cfa[t2] = u * u;                      // (1-t)**2
            cfb[t2] = (2.0 * u) * t;              // 2*(1-t)*t (ref assoc order)
            cfc[t2] = t * t;                      // t**2
        }
        if (t2 >= 56 && t2 < 60) out[LP_OFF  + b0 + (t2 - 56)] = LPV;
        if (t2 >= 60 && t2 < 64) out[ENT_OFF + b0 + (t2 - 60)] = ENV;
    }
    barrier_lds_only();

    // ---- pipelined paint/epilogue over 4 batches, 2 canvases ----
    #pragma unroll
    for (int bb = 0; bb < NBPB; ++bb) {
        if (bb > 0) {
            // epilogue of previous batch first: stores go in flight, then
            // this wave rolls straight into paint; no barrier between them
            // (epi touches canvas (bb-1)&1, paint touches canvas bb&1).
            do_epilogue(cnt[(bb - 1) & 1],
                        out + (size_t)(b0 + bb - 1) * CV * CV, tid);
        }
        do_paint(cnt[bb & 1], sp[bb], cfa, cfb, cfc, tid);
        barrier_lds_only();
    }
    do_epilogue(cnt[(NBPB - 1) & 1],
                out + (size_t)(b0 + NBPB - 1) * CV * CV, tid);
}

extern "C" void kernel_launch(void* const* d_in, const int* in_sizes, int n_in,
                              void* d_out, int out_size, void* d_ws, size_t ws_size,
                              hipStream_t stream) {
    const float* x    = (const float*)d_in[0];   // [2048, 256]
    const float* W    = (const float*)d_in[1];   // [256, 192]
    const float* bias = (const float*)d_in[2];   // [192]
    float* out = (float*)d_out;

    fused_kernel<<<NB / NBPB, 512, 0, stream>>>(x, W, bias, out);
}

// Round 12
// 157.909 us; speedup vs baseline: 1.0035x; 1.0035x over previous
//
#include <hip/hip_runtime.h>
#include <math.h>

// Problem constants (from reference)
#define NB      2048        // batch
#define DIM     256         // input dim
#define SC6     192         // S*6 = 32 splines * 6 params
#define CV      128         // canvas size
#define NT      50          // samples along curve
#define NBPB    4           // batches per block (W amortization)
#define CWORDS  (CV * CV / 4)   // 4096 u8-packed words per canvas
// W_STAMP = -0.07, BG = 0.3, SCALE = 1e-4

// log_prob per batch = 192*( -ln(1e-4) - 0.5*ln(2*pi) )  (raw == mu exactly)
// entropy  per batch = 192*( 0.5 + 0.5*ln(2*pi) + ln(1e-4) )
#define LPV  (1591.9491530441301f)
#define ENV  (-1495.9491530441301f)

// Output layout (flat, return order): sketch | log_prob | entropy | sample
#define SKETCH_N   ((size_t)NB * CV * CV)     // 33,554,432
#define LP_OFF     (SKETCH_N)
#define ENT_OFF    (LP_OFF + NB)
#define SAMPLE_OFF (ENT_OFF + NB)

typedef float vfloat4 __attribute__((ext_vector_type(4)));

// Workgroup barrier waiting ONLY on LDS ops (lgkmcnt), not global stores —
// __syncthreads() would emit s_waitcnt vmcnt(0) and drain epilogue stores on
// the critical path. All cross-phase deps here are LDS-only.
__device__ __forceinline__ void barrier_lds_only() {
    asm volatile("s_waitcnt lgkmcnt(0)\n\ts_barrier" ::: "memory");
}

// Paint one batch's 32 splines into canvas cnv (u8-packed, per-row rotation).
// Thread's spline s = tid&31 is LOOP-INVARIANT: the 6 spline params are
// hoisted to registers (was 6 ds_read_b64 of 32-distinct-addresses PER POINT
// -> now per batch; cf reads stay in LDS but are half-wave-uniform
// broadcasts, near-free). Expression order unchanged -> bit-identical coords.
__device__ __forceinline__ void do_paint(
    unsigned int* __restrict__ cnv,
    const double (* __restrict__ spb)[32],
    const double* __restrict__ cfa, const double* __restrict__ cfb,
    const double* __restrict__ cfc, int tid)
{
    const int s = tid & 31;
    const double P0x = spb[0][s], P0y = spb[1][s];
    const double P1x = spb[2][s], P1y = spb[3][s];
    const double P2x = spb[4][s], P2y = spb[5][s];

    for (int i = tid; i < 32 * NT; i += 512) {
        int kraw = i >> 5;                    // 0..49
        int k    = (kraw * 9) % 50;           // bijection, spreads t per wave
        double a  = cfa[k];
        double bq = cfb[k];
        double c  = cfc[k];
        double px = a * P0x + bq * P1x + c * P2x;  // same op order as prior
        double py = a * P0y + bq * P1y + c * P2y;  // passing rounds
        int cx = (int)rint(px);               // round-half-even == np.round
        int cy = (int)rint(py);

        // clipped y-triple -> u8 increments for 1-2 adjacent 4-px words
        int y0 = min(max(cy - 1, 0), CV - 1);
        int y1 = min(max(cy,     0), CV - 1);
        int y2 = min(max(cy + 1, 0), CV - 1);
        int cb = y0 >> 2;                     // base word-column (0..31)
        unsigned incA = 1u << ((y0 & 3) << 3);
        unsigned incB = 0u;
        unsigned i1 = 1u << ((y1 & 3) << 3);
        unsigned i2 = 1u << ((y2 & 3) << 3);
        if ((y1 >> 2) == cb) incA += i1; else incB += i1;
        if ((y2 >> 2) == cb) incA += i2; else incB += i2;

        int x0 = min(max(cx - 1, 0), CV - 1);
        int x1 = min(max(cx,     0), CV - 1);
        int x2 = min(max(cx + 1, 0), CV - 1);
        int rows[3] = {x0, x1, x2};
        #pragma unroll
        for (int r = 0; r < 3; ++r) {
            int xi = rows[r];
            int base = xi << 5;
            atomicAdd(&cnv[base + ((cb + xi) & 31)], incA);
            if (incB) atomicAdd(&cnv[base + ((cb + 1 + xi) & 31)], incB);
        }
    }
}

// Emit one batch's canvas: clip(0.3-0.07*count,0,1), float4 cached stores;
// re-zeros the canvas in passing (next paint into it needs zeros).
__device__ __forceinline__ void do_epilogue(
    unsigned int* __restrict__ cnv, float* __restrict__ outb, int tid)
{
    vfloat4* ob = (vfloat4*)outb;
    for (int w = tid; w < CWORDS; w += 512) {
        int xi  = w >> 5;                     // row
        int idx = (xi << 5) + (((w & 31) + xi) & 31);
        unsigned v = cnv[idx];
        cnv[idx] = 0u;
        vfloat4 r;
        r.x = fminf(fmaxf(0.3f - 0.07f * (float)( v        & 255u), 0.0f), 1.0f);
        r.y = fminf(fmaxf(0.3f - 0.07f * (float)((v >>  8) & 255u), 0.0f), 1.0f);
        r.z = fminf(fmaxf(0.3f - 0.07f * (float)((v >> 16) & 255u), 0.0f), 1.0f);
        r.w = fminf(fmaxf(0.3f - 0.07f * (float)( v >> 24        ), 0.0f), 1.0f);
        ob[w] = r;                            // cached store -> L2
    }
}

// ---------------------------------------------------------------------------
// Fused kernel, one block (512 thr) per FOUR batches; grid 512 = 2 blocks/CU.
//   phase 0: gemm (waves 0-2, f64 bit-exact chains) || zero A+B, coeff table
//   phase k (k=1..3): epilogue(batch k-1) then immediately (no barrier)
//            paint(batch k) into the other canvas; one lgkm-only barrier.
//   tail:    epilogue(batch 3).
// ---------------------------------------------------------------------------
__global__ __launch_bounds__(512) void fused_kernel(
    const float* __restrict__ x, const float* __restrict__ W,
    const float* __restrict__ bias, float* __restrict__ out)
{
    __shared__ unsigned int cnt[2][CWORDS];       // 2 × 16 KB u8-packed
    __shared__ double sp[NBPB][6][32];            // SoA params*128, 4 batches
    __shared__ double cfa[NT], cfb[NT], cfc[NT];  // (1-t)^2, 2(1-t)t, t^2

    const int b0  = blockIdx.x * NBPB;
    const int tid = threadIdx.x;

    if (tid < SC6) {
        // ---- gemm + sigmoid, 4 batches, W loaded once (f64 exact chains) ----
        const int j = tid;
        const float* xb = x + (size_t)b0 * DIM;   // wave-uniform -> s_load
        double a0 = 0.0, a1 = 0.0, a2 = 0.0, a3 = 0.0;
        #pragma unroll 8
        for (int d = 0; d < DIM; ++d) {
            double wd = (double)W[d * SC6 + j];
            a0 = fma((double)xb[d],           wd, a0);
            a1 = fma((double)xb[DIM + d],     wd, a1);
            a2 = fma((double)xb[2 * DIM + d], wd, a2);
            a3 = fma((double)xb[3 * DIM + d], wd, a3);
        }
        double bj = (double)bias[j];
        double s0 = 1.0 / (1.0 + exp(-(a0 + bj)));
        double s1 = 1.0 / (1.0 + exp(-(a1 + bj)));
        double s2 = 1.0 / (1.0 + exp(-(a2 + bj)));
        double s3 = 1.0 / (1.0 + exp(-(a3 + bj)));
        out[SAMPLE_OFF + (size_t)b0 * SC6 + j]       = (float)s0;
        out[SAMPLE_OFF + (size_t)(b0 + 1) * SC6 + j] = (float)s1;
        out[SAMPLE_OFF + (size_t)(b0 + 2) * SC6 + j] = (float)s2;
        out[SAMPLE_OFF + (size_t)(b0 + 3) * SC6 + j] = (float)s3;
        sp[0][j % 6][j / 6] = s0 * 128.0;         // CANVAS scale, SoA
        sp[1][j % 6][j / 6] = s1 * 128.0;
        sp[2][j % 6][j / 6] = s2 * 128.0;
        sp[3][j % 6][j / 6] = s3 * 128.0;
    } else {
        // ---- waves 3-7: zero BOTH canvases + coeff table + constants ----
        const int t2 = tid - SC6;                 // 0..319
        uint4* c4 = (uint4*)&cnt[0][0];           // 2048 uint4 words
        uint4 z = make_uint4(0u, 0u, 0u, 0u);
        for (int w = t2; w < 2048; w += 320) c4[w] = z;
        if (t2 < NT) {
            // np.linspace(0,1,50): t_k = k*fl64(1/49), endpoint forced to 1.0
            double t = (t2 == NT - 1) ? 1.0 : (double)t2 * (1.0 / 49.0);
            double u = 1.0 - t;
            cfa[t2] = u * u;                      // (1-t)**2
            cfb[t2] = (2.0 * u) * t;              // 2*(1-t)*t (ref assoc order)
            cfc[t2] = t * t;                      // t**2
        }
        if (t2 >= 56 && t2 < 60) out[LP_OFF  + b0 + (t2 - 56)] = LPV;
        if (t2 >= 60 && t2 < 64) out[ENT_OFF + b0 + (t2 - 60)] = ENV;
    }
    barrier_lds_only();

    // ---- pipelined paint/epilogue over 4 batches, 2 canvases ----
    #pragma unroll
    for (int bb = 0; bb < NBPB; ++bb) {
        if (bb > 0) {
            // epilogue of previous batch first: stores go in flight, then
            // this wave rolls straight into paint (disjoint canvases).
            do_epilogue(cnt[(bb - 1) & 1],
                        out + (size_t)(b0 + bb - 1) * CV * CV, tid);
        }
        do_paint(cnt[bb & 1], sp[bb], cfa, cfb, cfc, tid);
        barrier_lds_only();
    }
    do_epilogue(cnt[(NBPB - 1) & 1],
                out + (size_t)(b0 + NBPB - 1) * CV * CV, tid);
}

extern "C" void kernel_launch(void* const* d_in, const int* in_sizes, int n_in,
                              void* d_out, int out_size, void* d_ws, size_t ws_size,
                              hipStream_t stream) {
    const float* x    = (const float*)d_in[0];   // [2048, 256]
    const float* W    = (const float*)d_in[1];   // [256, 192]
    const float* bias = (const float*)d_in[2];   // [192]
    float* out = (float*)d_out;

    fused_kernel<<<NB / NBPB, 512, 0, stream>>>(x, W, bias, out);
}